// Round 8
// baseline (16.599 us; speedup 1.0000x reference)
//
#include <hip/hip_runtime.h>

#pragma float_control(precise, on)
#pragma STDC FP_CONTRACT OFF

#define SIGNAL_LENGTH 2048
#define NUM_ITERATIONS 3
#define STEP_SIZE 0.001f
// 10/4/2048 = 5 * 2^-12, exact in f32
#define DERIV_STEP 0.001220703125f
// RN_f32(1/0.00244140625) = RN(409.6) = 409.600006103515625
#define RCP_TWO_DERIV_STEP 409.6f

// Opaque value barrier: pins each f32 intermediate in a VGPR so OUR compiler
// cannot contract/reassociate/re-lower anything regardless of harness flags.
// The problem amplifies iteration-1 rounding differences by ~x1000/iter, so
// we must reproduce the reference's op-for-op f32 bit pattern.
__device__ __forceinline__ float opq(float x) {
    asm volatile("" : "+v"(x));
    return x;
}

// Linear-interp sample, separately-rounded f32, every step pinned:
//   idx = RN(pos*2047)  (multi-use -> never contracted in ref either)
//   w_right = idx - il  (exact, Sterbenz); w_left = 1 - w_right
//   v = RN(RN(vl*wl) + RN(vr*wr))
__device__ __forceinline__ float sample_v8(const float* __restrict__ row, float pos) {
#pragma clang fp contract(off)
    float idx = opq(pos * 2047.0f);
    int il = (int)floorf(idx);
    il = il < 0 ? 0 : (il > SIGNAL_LENGTH - 1 ? SIGNAL_LENGTH - 1 : il);
    int ir = (int)ceilf(idx);
    ir = ir < 0 ? 0 : (ir > SIGNAL_LENGTH - 1 ? SIGNAL_LENGTH - 1 : ir);
    float w_right = opq(idx - (float)il);
    float w_left  = opq(1.0f - w_right);
    float t0 = opq(row[il] * w_left);
    float t1 = opq(row[ir] * w_right);
    return opq(t0 + t1);
}

// Gradient + curvature sign.
// HYPOTHESIS UNDER TEST: reference lowered the gradient division-by-constant
// to multiplication by the f32-rounded reciprocal (x/c -> x*RN(1/c), the
// standard XLA/fast-math transform). RN(1/0.00244140625) = 409.6f (1 ulp off
// the true reciprocal), so this differs from a correctly-rounded divide on
// ~30% of gradients — exactly the class of mismatch still unexplained.
__device__ __forceinline__ void gradcurv_v8(const float* __restrict__ row, float pos,
                                            float& g, bool& curv_neg) {
#pragma clang fp contract(off)
    float pos_l = opq(fminf(fmaxf(opq(pos - DERIV_STEP), 0.0f), 1.0f));
    float pos_r = opq(fminf(fmaxf(opq(pos + DERIV_STEP), 0.0f), 1.0f));
    float v  = sample_v8(row, pos);
    float vl = sample_v8(row, pos_l);
    float vr = sample_v8(row, pos_r);
    float diff = opq(vr - vl);
    g = opq(diff * RCP_TWO_DERIV_STEP);
    // curvature: divisor DERIV_STEP^2 positive constant under ANY lowering
    // (divide or reciprocal-multiply) preserves sign -> compare numerator.
    float twov = opq(2.0f * v);           // exact (power of 2)
    float num = opq(opq(vr - twov) + vl); // left-to-right
    curv_neg = num < 0.0f;
}

__global__ void grad_refine_v8_kernel(const float* __restrict__ signal,
                                      const float* __restrict__ peaks,
                                      float* __restrict__ out,
                                      int n_rows) {
#pragma clang fp contract(off)
    int tid = blockIdx.x * blockDim.x + threadIdx.x;
    if (tid >= n_rows) return;

    const float* __restrict__ row = signal + (size_t)tid * SIGNAL_LENGTH;
    float p1 = peaks[(size_t)tid * 3 + 0];
    float p2 = peaks[(size_t)tid * 3 + 2];

    #pragma unroll
    for (int it = 0; it < NUM_ITERATIONS; ++it) {
        float g1, g2;
        bool n1, n2;
        gradcurv_v8(row, p1, g1, n1);
        gradcurv_v8(row, p2, g2, n2);
        // a = (-S*g)*mask; mask==1 exact; mask==0 -> +-0 and p+(+-0)==p.
        float a1 = n1 ? opq(-STEP_SIZE * g1) : 0.0f;
        float a2 = n2 ? opq(-STEP_SIZE * g2) : 0.0f;
        p1 = opq(fminf(fmaxf(opq(p1 + a1), 0.0f), 1.0f));
        p2 = opq(fminf(fmaxf(opq(p2 + a2), 0.0f), 1.0f));
    }
    float mid = opq(opq(p1 + p2) * 0.5f);  // /2 == *0.5 exactly

    bool ordered = p1 < p2;
    float o0 = ordered ? p1 : p2;
    float o2 = ordered ? p2 : p1;

    out[(size_t)tid * 3 + 0] = o0;
    out[(size_t)tid * 3 + 1] = mid;
    out[(size_t)tid * 3 + 2] = o2;
}

extern "C" void kernel_launch(void* const* d_in, const int* in_sizes, int n_in,
                              void* d_out, int out_size, void* d_ws, size_t ws_size,
                              hipStream_t stream) {
    // Inputs identified by size: signal = 65536*2048, peaks = 65536*3.
    const float* signal = (const float*)d_in[0];
    const float* peaks  = (const float*)d_in[1];
    if (n_in >= 2 && in_sizes[0] < in_sizes[1]) {
        signal = (const float*)d_in[1];
        peaks  = (const float*)d_in[0];
    }
    float* out = (float*)d_out;

    int n_rows = out_size / 3;
    if (n_rows <= 0) n_rows = 65536;

    int block = 256;
    int grid = (n_rows + block - 1) / block;
    grad_refine_v8_kernel<<<grid, block, 0, stream>>>(signal, peaks, out, n_rows);
}